// Round 3
// baseline (356.033 us; speedup 1.0000x reference)
//
#include <hip/hip_runtime.h>
#include <cstdint>
#include <cstddef>

// ---------------------------------------------------------------------------
// Style2ResidualBlock1DSrc: modulated conv1d (StyleGAN2-style) on MI355X.
// R6: FUSE all 4 stages into one persistent kernel + software grid barrier.
//  Evidence: gemm is 54-62us but total is 181-190us -> ~120us lives in the
//  3 prep kernels + inter-kernel serialization. Fusing removes the gaps and
//  runs transpose+demod concurrently across blocks.
//  - 512 blocks x 256 thr (= R4 gemm geometry), 2 blocks/CU exact capacity
//    (LDS 41.4KB x2 <= 160KB, VGPR <= 256 via launch_bounds) -> all blocks
//    co-resident -> software grid barrier is safe (device-scope atomics +
//    __threadfence per G12/G16; bounded spin so a bug fails, never hangs).
//  - Stage A: style s[b][i] on blocks 0..127.
//  - Stage B: each block: 8 transpose+modulate tiles, then 1 demod row + Wb.
//  - Stage C: R4 2-barrier gemm verbatim (R5 phase experiment reverted: it
//    regressed 58->62us; barrier count tripled, no traffic change).
// Factorization kept: A = bf16 Wb[3][512][512] (L2-resident), s folded into
// xT, demod applied in fp32 epilogue.
// ---------------------------------------------------------------------------

#define LIN_SCALE  0.0625f           // 1/sqrt(256)
#define CONV_SCALE 0.014731391f      // 1/sqrt(512*9)

#define B_   16
#define CIN  512
#define COUT 512
#define T_   2048
#define TP   2050                    // T + 2 pad rows

typedef __bf16 bf16x8 __attribute__((ext_vector_type(8)));
typedef float  f32x4  __attribute__((ext_vector_type(4)));
typedef unsigned short u16x8 __attribute__((ext_vector_type(8)));
typedef unsigned short u16x2 __attribute__((ext_vector_type(2)));

#define AS1 __attribute__((address_space(1)))
#define AS3 __attribute__((address_space(3)))

__device__ inline unsigned short f2bf(float f) {
  __bf16 h = (__bf16)f;              // RNE fptrunc
  return __builtin_bit_cast(unsigned short, h);
}

__global__ void init_kernel(unsigned* sync) { sync[0] = 0u; sync[1] = 0u; }

// Device-wide barrier: all gridDim.x blocks must be co-resident (they are:
// grid sized to exact 2-blocks/CU capacity). Release fence + agent-scope
// atomics make prior global writes visible across XCD L2s.
__device__ inline void grid_barrier(unsigned* cnt, unsigned* gen, unsigned nb) {
  __syncthreads();
  if (threadIdx.x == 0) {
    __threadfence();                 // release my block's writes (L2 wb)
    const unsigned g = __hip_atomic_load(gen, __ATOMIC_RELAXED, __HIP_MEMORY_SCOPE_AGENT);
    const unsigned a = __hip_atomic_fetch_add(cnt, 1u, __ATOMIC_ACQ_REL, __HIP_MEMORY_SCOPE_AGENT);
    if (a == nb - 1u) {
      __hip_atomic_store(cnt, 0u, __ATOMIC_RELAXED, __HIP_MEMORY_SCOPE_AGENT);
      __hip_atomic_store(gen, g + 1u, __ATOMIC_RELEASE, __HIP_MEMORY_SCOPE_AGENT);
    } else {
      int t = 0;
      while (__hip_atomic_load(gen, __ATOMIC_ACQUIRE, __HIP_MEMORY_SCOPE_AGENT) == g) {
        __builtin_amdgcn_s_sleep(2);
        if (++t > (1 << 24)) break;  // safety valve: fail verify, never hang
      }
    }
    __threadfence();                 // acquire: invalidate stale lines
  }
  __syncthreads();
}

// ---------------------------------------------------------------------------
__global__ __launch_bounds__(256, 2) void mega_kernel(
    const float* __restrict__ x, const float* __restrict__ c_src,
    const float* __restrict__ c_trg, const float* __restrict__ sw,
    const float* __restrict__ sb, const float* __restrict__ weight,
    float* __restrict__ s, float* __restrict__ demod,
    unsigned short* __restrict__ Wb, unsigned short* __restrict__ xT,
    float* __restrict__ out, unsigned* __restrict__ sync) {
  __shared__ __align__(16) char smem[41472];   // union of all stage layouts
  const int id  = blockIdx.x;
  const int tid = threadIdx.x;

  // ================= stage A: style linear (blocks 0..127) =================
  if (id < 128) {
    float* c = (float*)smem;                   // 256 floats
    const int b = id >> 3, bx = id & 7;
    c[tid] = (tid < 128) ? c_src[b * 128 + tid] : c_trg[b * 128 + tid - 128];
    __syncthreads();
    const int w = tid >> 6, lane = tid & 63;
    #pragma unroll
    for (int rr = 0; rr < 16; ++rr) {
      const int i = bx * 64 + w * 16 + rr;
      const float* row = sw + (size_t)i * 256;
      float acc = row[lane] * c[lane] + row[lane + 64] * c[lane + 64]
                + row[lane + 128] * c[lane + 128] + row[lane + 192] * c[lane + 192];
      #pragma unroll
      for (int off = 32; off; off >>= 1) acc += __shfl_down(acc, off, 64);
      if (lane == 0) s[b * 512 + i] = acc * LIN_SCALE + sb[i];
    }
  }
  grid_barrier(sync, sync + 1, gridDim.x);

  // ============ stage B1: transpose + pad + s-modulate (8 tiles) ===========
  {
    float* tile = (float*)smem;                // [64][65] = 16640 B
    float* ss   = (float*)(smem + 64 * 65 * 4);  // 64 floats
    const int b   = id >> 5;                   // 16
    const int i0  = ((id >> 2) & 7) * 64;      // 8
    const int t0b = (id & 3) * 512;            // 4 * (8 units of 64)
    if (tid < 64) ss[tid] = s[(size_t)b * 512 + i0 + tid];

    const int lr = tid >> 4;                   // 0..15
    const int lc = (tid & 15) * 4;             // float4
    const int st = tid >> 3;                   // 0..31
    const int si = (tid & 7) * 8;              // 16B

    for (int u = 0; u < 8; ++u) {
      const int t0 = t0b + u * 64;
      if (u) __syncthreads();                  // prev readers done
      const float* xb = x + ((size_t)b * CIN + i0) * T_ + t0;
      #pragma unroll
      for (int p = 0; p < 4; ++p) {
        const int r = p * 16 + lr;
        const float4 v = *(const float4*)(xb + (size_t)r * T_ + lc);
        tile[r * 65 + lc + 0] = v.x; tile[r * 65 + lc + 1] = v.y;
        tile[r * 65 + lc + 2] = v.z; tile[r * 65 + lc + 3] = v.w;
      }
      if (t0 == 0 && tid < 8)
        *(u16x8*)&xT[(size_t)b * TP * CIN + i0 + tid * 8] = (u16x8){0,0,0,0,0,0,0,0};
      if (t0 == T_ - 64 && tid < 8)
        *(u16x8*)&xT[((size_t)b * TP + TP - 1) * CIN + i0 + tid * 8] = (u16x8){0,0,0,0,0,0,0,0};
      __syncthreads();
      float sv[8];
      #pragma unroll
      for (int q = 0; q < 8; ++q) sv[q] = ss[si + q];
      unsigned short* xTb = xT + ((size_t)b * TP + 1 + t0) * CIN + i0;
      #pragma unroll
      for (int p = 0; p < 2; ++p) {
        const int t = p * 32 + st;
        u16x8 v;
        #pragma unroll
        for (int q = 0; q < 8; ++q) v[q] = f2bf(tile[(si + q) * 65 + t] * sv[q]);
        *(u16x8*)&xTb[(size_t)t * CIN + si] = v;
      }
    }
  }
  __syncthreads();                             // tile readers done before reuse

  // ============ stage B2: demod[b][o] + base bf16 Wb (o = id) ==============
  {
    float* wsh     = (float*)smem;             // 1536 floats (6144 B)
    float* svs     = (float*)(smem + 6144);    // 8192 floats (32768 B)
    float* partial = (float*)(smem + 38912);   // 16*4 floats (256 B)
    const int o = id;

    #pragma unroll
    for (int j = tid; j < 384; j += 256)
      ((float4*)wsh)[j] = ((const float4*)(weight + (size_t)o * 1536))[j];
    #pragma unroll
    for (int j = tid; j < 2048; j += 256)
      ((float4*)svs)[j] = ((const float4*)s)[j];
    __syncthreads();

    float wr[6];
    #pragma unroll
    for (int q = 0; q < 6; ++q) wr[q] = wsh[tid * 6 + q] * CONV_SCALE;

    #pragma unroll
    for (int k = 0; k < 3; ++k) {
      u16x2 v;
      v.x = f2bf(wr[k]);
      v.y = f2bf(wr[3 + k]);
      *(u16x2*)&Wb[((size_t)(k * 512 + o)) * 512 + 2 * tid] = v;
    }

    const int lane = tid & 63, w = tid >> 6;
    float ssb[16];
    #pragma unroll
    for (int b = 0; b < 16; ++b) {
      const float s0 = svs[b * 512 + 2 * tid];
      const float s1 = svs[b * 512 + 2 * tid + 1];
      float ssq = 0.f;
      #pragma unroll
      for (int q = 0; q < 3; ++q) { float v = wr[q] * s0; ssq += v * v; }
      #pragma unroll
      for (int q = 3; q < 6; ++q) { float v = wr[q] * s1; ssq += v * v; }
      ssb[b] = ssq;
    }
    #pragma unroll
    for (int b = 0; b < 16; ++b) {
      float ssq = ssb[b];
      #pragma unroll
      for (int off = 32; off; off >>= 1) ssq += __shfl_down(ssq, off, 64);
      if (lane == 0) partial[b * 4 + w] = ssq;
    }
    __syncthreads();
    if (tid < 16)
      demod[(size_t)tid * 512 + o] =
          rsqrtf(partial[tid * 4] + partial[tid * 4 + 1] + partial[tid * 4 + 2]
               + partial[tid * 4 + 3] + 1e-8f);
  }
  grid_barrier(sync, sync + 1, gridDim.x);

  // ================= stage C: gemm (R4 2-barrier, verbatim) ================
  {
    unsigned short* lA = (unsigned short*)smem;            // 24576 B
    unsigned short* lB = (unsigned short*)(smem + 24576);  // 16512 B

    // XCD b-grouping: 512 blocks; id==xcd (mod 8); 2 batches per XCD.
    const int xcd = id & 7;
    const int j   = id >> 3;                 // 0..63
    const int b   = xcd + 8 * (j >> 5);      // 0..15
    const int r   = j & 31;
    const int o0  = (r >> 3) * 128;          // 4 o-blocks
    const int t0  = (r & 7) * 256;           // 8 t-blocks

    const int lane = tid & 63;
    const int wm   = ((tid >> 6) & 1) * 64;  // wave M offset
    const int wn   = (tid >> 7) * 128;       // wave N offset
    const int rl   = lane & 15;
    const int kc   = lane >> 4;              // chunk 0..3 within 32-wide row

    const unsigned short* gW = Wb + (size_t)o0 * 512;
    const unsigned short* gX = xT + ((size_t)b * TP + t0) * CIN;

    f32x4 acc[4][8];
    #pragma unroll
    for (int i = 0; i < 4; ++i)
      #pragma unroll
      for (int jj = 0; jj < 8; ++jj) acc[i][jj] = (f32x4){0.f, 0.f, 0.f, 0.f};

    for (int kk = 0; kk < 16; ++kk) {
      const int i0 = kk * 32;
      __syncthreads();                       // previous compute done
      #pragma unroll
      for (int q = 0; q < 6; ++q) {
        const int ci  = q * 256 + tid;
        const int row = ci >> 2;             // tap*128 + ar
        const int tap = row >> 7;
        const int ar  = row & 127;
        const int gc  = ((ci & 3) ^ ((ar >> 1) & 3)) * 8;
        __builtin_amdgcn_global_load_lds(
            (const AS1 void*)(gW + (size_t)tap * 262144 + (size_t)ar * 512 + i0 + gc),
            (AS3 void*)(&lA[ci * 8]), 16, 0, 0);
      }
      #pragma unroll
      for (int q = 0; q < 4; ++q) {
        const int ci  = q * 256 + tid;
        const int row = ci >> 2;
        const int gc  = ((ci & 3) ^ ((row >> 1) & 3)) * 8;
        __builtin_amdgcn_global_load_lds(
            (const AS1 void*)(gX + (size_t)row * CIN + i0 + gc),
            (AS3 void*)(&lB[ci * 8]), 16, 0, 0);
      }
      if (tid < 8) {
        const int ci  = 1024 + tid;
        const int row = ci >> 2;             // 256, 257
        const int gc  = ((ci & 3) ^ ((row >> 1) & 3)) * 8;
        __builtin_amdgcn_global_load_lds(
            (const AS1 void*)(gX + (size_t)row * CIN + i0 + gc),
            (AS3 void*)(&lB[ci * 8]), 16, 0, 0);
      }
      __syncthreads();                       // staging visible

      #pragma unroll
      for (int tap = 0; tap < 3; ++tap) {
        bf16x8 af[4], bfr[8];
        #pragma unroll
        for (int mi = 0; mi < 4; ++mi) {
          const int ra = wm + mi * 16 + rl;
          af[mi] = *(const bf16x8*)&lA[((tap * 128 + ra) * 4 + (kc ^ ((ra >> 1) & 3))) * 8];
        }
        #pragma unroll
        for (int ni = 0; ni < 8; ++ni) {
          const int rb = wn + ni * 16 + rl + tap;
          bfr[ni] = *(const bf16x8*)&lB[(rb * 4 + (kc ^ ((rb >> 1) & 3))) * 8];
        }
        #pragma unroll
        for (int mi = 0; mi < 4; ++mi)
          #pragma unroll
          for (int ni = 0; ni < 8; ++ni)
            acc[mi][ni] = __builtin_amdgcn_mfma_f32_16x16x32_bf16(af[mi], bfr[ni], acc[mi][ni], 0, 0, 0);
      }
    }

    // epilogue: D row = (lane>>4)*4 + reg, col = lane&15 (m89 mapping); x demod
    float* ob = out + ((size_t)b * COUT + o0 + wm) * T_ + t0 + wn;
    const float* dm = demod + (size_t)b * 512 + o0 + wm;
    const int rrow = (lane >> 4) * 4;
    const int ccol = lane & 15;
    #pragma unroll
    for (int mi = 0; mi < 4; ++mi) {
      float dr[4];
      #pragma unroll
      for (int rr = 0; rr < 4; ++rr) dr[rr] = dm[mi * 16 + rrow + rr];
      #pragma unroll
      for (int ni = 0; ni < 8; ++ni)
        #pragma unroll
        for (int rr = 0; rr < 4; ++rr)
          ob[(size_t)(mi * 16 + rrow + rr) * T_ + ni * 16 + ccol] = acc[mi][ni][rr] * dr[rr];
    }
  }
}

// ---------------------------------------------------------------------------
extern "C" void kernel_launch(void* const* d_in, const int* in_sizes, int n_in,
                              void* d_out, int out_size, void* d_ws, size_t ws_size,
                              hipStream_t stream) {
  const float* x       = (const float*)d_in[0];   // [16,512,2048]
  const float* c_src   = (const float*)d_in[1];   // [16,128]
  const float* c_trg   = (const float*)d_in[2];   // [16,128]
  const float* style_w = (const float*)d_in[3];   // [512,256]
  const float* style_b = (const float*)d_in[4];   // [512]
  const float* weight  = (const float*)d_in[5];   // [1,512,512,3]
  float* out = (float*)d_out;

  // workspace: s fp32 [16][512] @0; demod fp32 [16][512] @32768;
  //            Wb bf16 [3][512][512] @65536; xT bf16 [16][2050][512] @1638400;
  //            sync 2x u32 @35225600
  char* ws = (char*)d_ws;
  float* s_buf          = (float*)ws;
  float* demod_buf      = (float*)(ws + 32768);
  unsigned short* Wb    = (unsigned short*)(ws + 65536);
  unsigned short* xTbuf = (unsigned short*)(ws + 65536 + 1572864);
  unsigned* sync        = (unsigned*)(ws + 35225600);

  init_kernel<<<dim3(1), 1, 0, stream>>>(sync);
  mega_kernel<<<dim3(512), 256, 0, stream>>>(x, c_src, c_trg, style_w, style_b,
                                             weight, s_buf, demod_buf, Wb, xTbuf,
                                             out, sync);
}

// Round 4
// 196.631 us; speedup vs baseline: 1.8107x; 1.8107x over previous
//
#include <hip/hip_runtime.h>
#include <cstdint>
#include <cstddef>

// ---------------------------------------------------------------------------
// Style2ResidualBlock1DSrc: modulated conv1d (StyleGAN2-style) on MI355X.
// R7: revert R6 fusion (prep kernels back to R4 verbatim; fixed ~80us is
// harness overhead, not launch gaps). Gemm rebuilt as the catalog's
// MINIMUM 2-phase stage-ahead loop:
//  - stage B(k+1) issued BEFORE computing tile k; ONE vmcnt(0)+barrier per
//    K-step (latency hidden under ~1500cyc of MFMA), 16 barriers vs 32.
//  - A-tile (Wb, 1.5MB L2-resident) no longer staged in LDS: MFMA B-operand
//    frags read DIRECT from L2 into regs (12 x 16B per wave per K-step,
//    hidden under previous tap's MFMAs). LDS = lB double-buffer only
//    (33KB) -> 2 blocks/CU with margin; LDS traffic -33%.
//  - MFMA operand order swapped: D = xT_frag * Wb_frag -> D rows = t.
//    Lane's 4 acc values consecutive in t -> float4 epilogue (32 stores vs
//    128), demod indexed by lane's fixed o-column (4 scalar loads).
// Factorization kept: s folded into xT, demod applied in fp32 epilogue.
// ---------------------------------------------------------------------------

#define LIN_SCALE  0.0625f           // 1/sqrt(256)
#define CONV_SCALE 0.014731391f      // 1/sqrt(512*9)

#define B_   16
#define CIN  512
#define COUT 512
#define T_   2048
#define TP   2050                    // T + 2 pad rows

typedef __bf16 bf16x8 __attribute__((ext_vector_type(8)));
typedef float  f32x4  __attribute__((ext_vector_type(4)));
typedef unsigned short u16x8 __attribute__((ext_vector_type(8)));
typedef unsigned short u16x2 __attribute__((ext_vector_type(2)));

#define AS1 __attribute__((address_space(1)))
#define AS3 __attribute__((address_space(3)))

__device__ inline unsigned short f2bf(float f) {
  __bf16 h = (__bf16)f;              // RNE fptrunc
  return __builtin_bit_cast(unsigned short, h);
}

// ---------------- 1. style linear: s[b][i] ----------------
__global__ __launch_bounds__(256) void style_kernel(const float* __restrict__ c_src,
                                                    const float* __restrict__ c_trg,
                                                    const float* __restrict__ sw,
                                                    const float* __restrict__ sb,
                                                    float* __restrict__ s) {
  __shared__ float c[256];
  const int b = blockIdx.y;
  const int tid = threadIdx.x;
  c[tid] = (tid < 128) ? c_src[b * 128 + tid] : c_trg[b * 128 + tid - 128];
  __syncthreads();
  const int w = tid >> 6, lane = tid & 63;
  #pragma unroll
  for (int rr = 0; rr < 16; ++rr) {
    const int i = blockIdx.x * 64 + w * 16 + rr;
    const float* row = sw + (size_t)i * 256;
    float acc = row[lane] * c[lane] + row[lane + 64] * c[lane + 64]
              + row[lane + 128] * c[lane + 128] + row[lane + 192] * c[lane + 192];
    #pragma unroll
    for (int off = 32; off; off >>= 1) acc += __shfl_down(acc, off, 64);
    if (lane == 0) s[b * 512 + i] = acc * LIN_SCALE + sb[i];
  }
}

// ---------------- 2. demod[b][o] + base bf16 weight Wb[tap][o][i] ----------------
__global__ __launch_bounds__(256) void demod_kernel(const float* __restrict__ weight,
                                                    const float* __restrict__ s,
                                                    float* __restrict__ demod,
                                                    unsigned short* __restrict__ Wb) {
  const int o = blockIdx.x;
  const int tid = threadIdx.x;
  __shared__ float wsh[1536];        // weight[o][:][:]
  __shared__ float svs[16 * 512];    // all style vectors (32 KB)
  __shared__ float partial[16][4];

  #pragma unroll
  for (int j = tid; j < 384; j += 256)
    ((float4*)wsh)[j] = ((const float4*)(weight + (size_t)o * 1536))[j];
  #pragma unroll
  for (int j = tid; j < 2048; j += 256)
    ((float4*)svs)[j] = ((const float4*)s)[j];
  __syncthreads();

  float wr[6];
  #pragma unroll
  for (int q = 0; q < 6; ++q) wr[q] = wsh[tid * 6 + q] * CONV_SCALE;

  // batch-independent bf16 base weight: Wb[k][o][i], i = 2*tid, 2*tid+1
  #pragma unroll
  for (int k = 0; k < 3; ++k) {
    u16x2 v;
    v.x = f2bf(wr[k]);
    v.y = f2bf(wr[3 + k]);
    *(u16x2*)&Wb[((size_t)(k * 512 + o)) * 512 + 2 * tid] = v;
  }

  const int lane = tid & 63, w = tid >> 6;
  float ssb[16];
  #pragma unroll
  for (int b = 0; b < 16; ++b) {
    const float s0 = svs[b * 512 + 2 * tid];
    const float s1 = svs[b * 512 + 2 * tid + 1];
    float ss = 0.f;
    #pragma unroll
    for (int q = 0; q < 3; ++q) { float v = wr[q] * s0; ss += v * v; }
    #pragma unroll
    for (int q = 3; q < 6; ++q) { float v = wr[q] * s1; ss += v * v; }
    ssb[b] = ss;
  }
  #pragma unroll
  for (int b = 0; b < 16; ++b) {
    float ss = ssb[b];
    #pragma unroll
    for (int off = 32; off; off >>= 1) ss += __shfl_down(ss, off, 64);
    if (lane == 0) partial[b][w] = ss;
  }
  __syncthreads();
  if (tid < 16)
    demod[(size_t)tid * 512 + o] =
        rsqrtf(partial[tid][0] + partial[tid][1] + partial[tid][2] + partial[tid][3] + 1e-8f);
}

// ---------------- 3. transpose + pad + s-modulate + bf16 ----------------
__global__ __launch_bounds__(256) void transpose_kernel(const float* __restrict__ x,
                                                        const float* __restrict__ s,
                                                        unsigned short* __restrict__ xT) {
  __shared__ float tile[64][65];
  __shared__ float ss[64];
  const int b = blockIdx.z, i0 = blockIdx.y * 64, t0 = blockIdx.x * 64;
  const int tid = threadIdx.x;

  if (tid < 64) ss[tid] = s[(size_t)b * 512 + i0 + tid];

  const int lr = tid >> 4;            // 0..15
  const int lc = (tid & 15) * 4;      // float4
  const float* xb = x + ((size_t)b * CIN + i0) * T_ + t0;
  #pragma unroll
  for (int p = 0; p < 4; ++p) {
    const int r = p * 16 + lr;
    const float4 v = *(const float4*)(xb + (size_t)r * T_ + lc);
    tile[r][lc + 0] = v.x; tile[r][lc + 1] = v.y;
    tile[r][lc + 2] = v.z; tile[r][lc + 3] = v.w;
  }
  // fused zero-pad of rows 0 and 2049 (no barrier dependency)
  if (blockIdx.x == 0 && tid < 8)
    *(u16x8*)&xT[(size_t)b * TP * CIN + i0 + tid * 8] = (u16x8){0,0,0,0,0,0,0,0};
  if (blockIdx.x == gridDim.x - 1 && tid < 8)
    *(u16x8*)&xT[((size_t)b * TP + TP - 1) * CIN + i0 + tid * 8] = (u16x8){0,0,0,0,0,0,0,0};
  __syncthreads();

  const int st = tid >> 3;            // 0..31
  const int si = (tid & 7) * 8;       // 16B
  float sv[8];
  #pragma unroll
  for (int q = 0; q < 8; ++q) sv[q] = ss[si + q];
  unsigned short* xTb = xT + ((size_t)b * TP + 1 + t0) * CIN + i0;
  #pragma unroll
  for (int p = 0; p < 2; ++p) {
    const int t = p * 32 + st;
    u16x8 v;
    #pragma unroll
    for (int q = 0; q < 8; ++q) v[q] = f2bf(tile[si + q][t] * sv[q]);
    *(u16x8*)&xTb[(size_t)t * CIN + si] = v;
  }
}

// ---------------- 4. main GEMM: minimum 2-phase, A-direct-from-L2 ----------------
// D[t-rows][o-cols]: acc = mfma(xT_frag(A-op, t rows), Wb_frag(B-op, o cols)).
// Block tile: t 256 x o 128; 4 waves 2(t)x2(o); wave tile t128 x o64 = 8x4 frags.
// lB[2][258 rows][32 k] bf16, chunk-swizzled c^((row>>1)&3), dbuf (33 KB).
// Wb frags read direct from L2 (no LDS stage): lane(rl,kc) reads 16B at
// row o0+wo+ni*16+rl, k=i0+kc*8. Per K-step: stage B(k+1); compute k;
// vmcnt(0); barrier.  (stage latency hidden under ~1500cyc of MFMA)
#define VMCNT0  asm volatile("s_waitcnt vmcnt(0)" ::: "memory")

#define STAGEB(buf, i0g) do {                                                 \
    _Pragma("unroll")                                                         \
    for (int q = 0; q < 4; ++q) {                                             \
      const int ci  = q * 256 + tid;                                          \
      const int row = ci >> 2;                                                \
      const int gc  = ((ci & 3) ^ ((row >> 1) & 3)) * 8;                      \
      __builtin_amdgcn_global_load_lds(                                       \
          (const AS1 void*)(gX + (size_t)row * CIN + (i0g) + gc),             \
          (AS3 void*)(&lB[buf][ci * 8]), 16, 0, 0);                           \
    }                                                                         \
    if (tid < 8) {                                                            \
      const int ci  = 1024 + tid;                                             \
      const int row = ci >> 2;                                                \
      const int gc  = ((ci & 3) ^ ((row >> 1) & 3)) * 8;                      \
      __builtin_amdgcn_global_load_lds(                                       \
          (const AS1 void*)(gX + (size_t)row * CIN + (i0g) + gc),             \
          (AS3 void*)(&lB[buf][ci * 8]), 16, 0, 0);                           \
    }                                                                         \
  } while (0)

__global__ __launch_bounds__(256, 2) void gemm_kernel(const unsigned short* __restrict__ Wb,
                                                      const unsigned short* __restrict__ xT,
                                                      const float* __restrict__ demod,
                                                      float* __restrict__ out) {
  __shared__ unsigned short lB[2][1032 * 8];   // 2 x 16512 B = 33 KB

  // XCD b-grouping: 512 blocks; id==xcd (mod 8); 2 batches per XCD.
  const int id  = blockIdx.x;
  const int xcd = id & 7;
  const int j   = id >> 3;                 // 0..63
  const int b   = xcd + 8 * (j >> 5);      // 0..15
  const int r   = j & 31;
  const int o0  = (r >> 3) * 128;          // 4 o-blocks
  const int t0  = (r & 7) * 256;           // 8 t-blocks

  const int tid  = threadIdx.x;
  const int lane = tid & 63;
  const int wt   = ((tid >> 6) & 1) * 128; // wave t offset (2 waves)
  const int wo   = (tid >> 7) * 64;        // wave o offset (2 waves)
  const int rl   = lane & 15;
  const int kc   = lane >> 4;              // k-chunk 0..3

  // per-lane Wb base: row = o0+wo+rl (+ni*16), k-byte = kc*8 elems (+i0)
  const unsigned short* gWl = Wb + ((size_t)(o0 + wo + rl)) * 512 + kc * 8;
  const unsigned short* gX  = xT + ((size_t)b * TP + t0) * CIN;

  f32x4 acc[8][4];                         // [t-frag][o-frag]
  #pragma unroll
  for (int i = 0; i < 8; ++i)
    #pragma unroll
    for (int jj = 0; jj < 4; ++jj) acc[i][jj] = (f32x4){0.f, 0.f, 0.f, 0.f};

  // prologue: stage K-step 0
  STAGEB(0, 0);
  VMCNT0;
  __builtin_amdgcn_s_barrier();

  for (int kk = 0; kk < 16; ++kk) {
    const int i0  = kk * 32;
    const int cur = kk & 1;
    if (kk < 15) STAGEB(cur ^ 1, i0 + 32);  // stage ahead: hidden under MFMAs

    // Wb frags direct from L2: 3 taps x 4 o-frags (12 x 16B per lane)
    bf16x8 wf[3][4];
    #pragma unroll
    for (int tap = 0; tap < 3; ++tap)
      #pragma unroll
      for (int ni = 0; ni < 4; ++ni)
        wf[tap][ni] = *(const bf16x8*)(gWl + (size_t)tap * 262144 + ni * 8192 + i0);

    #pragma unroll
    for (int tap = 0; tap < 3; ++tap) {
      bf16x8 xf[8];
      #pragma unroll
      for (int mi = 0; mi < 8; ++mi) {
        const int rb = wt + mi * 16 + rl + tap;
        xf[mi] = *(const bf16x8*)&lB[cur][(rb * 4 + (kc ^ ((rb >> 1) & 3))) * 8];
      }
      #pragma unroll
      for (int mi = 0; mi < 8; ++mi)
        #pragma unroll
        for (int ni = 0; ni < 4; ++ni)
          acc[mi][ni] = __builtin_amdgcn_mfma_f32_16x16x32_bf16(xf[mi], wf[tap][ni], acc[mi][ni], 0, 0, 0);
    }

    VMCNT0;                                // drains stage(k+1); ~free (covered)
    __builtin_amdgcn_s_barrier();
  }

  // epilogue: D col = lane&15 -> o; row = (lane>>4)*4+reg -> t (consecutive!)
  const int ccol = lane & 15;
  const int trow = (lane >> 4) * 4;
  float dmv[4];
  #pragma unroll
  for (int ni = 0; ni < 4; ++ni)
    dmv[ni] = demod[(size_t)b * 512 + o0 + wo + ni * 16 + ccol];
  float* ob = out + ((size_t)b * COUT + o0 + wo + ccol) * T_ + t0 + wt + trow;
  #pragma unroll
  for (int mi = 0; mi < 8; ++mi)
    #pragma unroll
    for (int ni = 0; ni < 4; ++ni) {
      f32x4 v = acc[mi][ni];
      v.x *= dmv[ni]; v.y *= dmv[ni]; v.z *= dmv[ni]; v.w *= dmv[ni];
      *(f32x4*)&ob[(size_t)ni * 16 * T_ + mi * 16] = v;
    }
}

// ---------------------------------------------------------------------------
extern "C" void kernel_launch(void* const* d_in, const int* in_sizes, int n_in,
                              void* d_out, int out_size, void* d_ws, size_t ws_size,
                              hipStream_t stream) {
  const float* x       = (const float*)d_in[0];   // [16,512,2048]
  const float* c_src   = (const float*)d_in[1];   // [16,128]
  const float* c_trg   = (const float*)d_in[2];   // [16,128]
  const float* style_w = (const float*)d_in[3];   // [512,256]
  const float* style_b = (const float*)d_in[4];   // [512]
  const float* weight  = (const float*)d_in[5];   // [1,512,512,3]
  float* out = (float*)d_out;

  // workspace: s fp32 [16][512] @0; demod fp32 [16][512] @32768;
  //            Wb bf16 [3][512][512] @65536; xT bf16 [16][2050][512] @1638400
  char* ws = (char*)d_ws;
  float* s_buf          = (float*)ws;
  float* demod_buf      = (float*)(ws + 32768);
  unsigned short* Wb    = (unsigned short*)(ws + 65536);
  unsigned short* xTbuf = (unsigned short*)(ws + 65536 + 1572864);

  style_kernel<<<dim3(8, 16), 256, 0, stream>>>(c_src, c_trg, style_w, style_b, s_buf);
  demod_kernel<<<dim3(COUT), 256, 0, stream>>>(weight, s_buf, demod_buf, Wb);
  transpose_kernel<<<dim3(T_ / 64, CIN / 64, B_), 256, 0, stream>>>(x, s_buf, xTbuf);
  gemm_kernel<<<dim3(512), 256, 0, stream>>>(Wb, xTbuf, demod_buf, out);
}

// Round 5
// 186.896 us; speedup vs baseline: 1.9050x; 1.0521x over previous
//
#include <hip/hip_runtime.h>
#include <cstdint>
#include <cstddef>

// ---------------------------------------------------------------------------
// Style2ResidualBlock1DSrc: modulated conv1d (StyleGAN2-style) on MI355X.
// R8: the catalog's MINIMUM 2-phase recipe, implemented exactly:
//   prologue: STAGE(buf0); vmcnt(0); barrier;
//   loop:     STAGE(buf^1, k+1)  [coalesced global_load_lds, issued FIRST]
//             ds_read frags(buf) ; 96 MFMA/wave (setprio 1)
//             vmcnt(0); barrier   [ONE barrier per K-step]
//  - R4 had stage->drain->compute (latency exposed; 32 barriers). R5 had 6
//    barriers/step. R7's scattered per-lane A-reads (stride 1024B gather)
//    were the regression -> A goes back to LDS, coalesced staging.
//  - Both operands double-buffered: LDS 112.25KB -> 1 block/CU, 8 waves,
//    BM=128(o) BN=512(t) BK=32, wave tile 64x128 (R5's verified frag math).
//  - MFMA phase ~3700cyc/CU >> L2/HBM latency -> end-of-step vmcnt(0) ~free.
// Prep kernels: R4 verbatim. Factorization kept: s folded into xT, demod in
// fp32 epilogue, A = bf16 Wb[3][512][512] L2-resident.
// ---------------------------------------------------------------------------

#define LIN_SCALE  0.0625f           // 1/sqrt(256)
#define CONV_SCALE 0.014731391f      // 1/sqrt(512*9)

#define B_   16
#define CIN  512
#define COUT 512
#define T_   2048
#define TP   2050                    // T + 2 pad rows

typedef __bf16 bf16x8 __attribute__((ext_vector_type(8)));
typedef float  f32x4  __attribute__((ext_vector_type(4)));
typedef unsigned short u16x8 __attribute__((ext_vector_type(8)));
typedef unsigned short u16x2 __attribute__((ext_vector_type(2)));

#define AS1 __attribute__((address_space(1)))
#define AS3 __attribute__((address_space(3)))

__device__ inline unsigned short f2bf(float f) {
  __bf16 h = (__bf16)f;              // RNE fptrunc
  return __builtin_bit_cast(unsigned short, h);
}

// ---------------- 1. style linear: s[b][i] ----------------
__global__ __launch_bounds__(256) void style_kernel(const float* __restrict__ c_src,
                                                    const float* __restrict__ c_trg,
                                                    const float* __restrict__ sw,
                                                    const float* __restrict__ sb,
                                                    float* __restrict__ s) {
  __shared__ float c[256];
  const int b = blockIdx.y;
  const int tid = threadIdx.x;
  c[tid] = (tid < 128) ? c_src[b * 128 + tid] : c_trg[b * 128 + tid - 128];
  __syncthreads();
  const int w = tid >> 6, lane = tid & 63;
  #pragma unroll
  for (int rr = 0; rr < 16; ++rr) {
    const int i = blockIdx.x * 64 + w * 16 + rr;
    const float* row = sw + (size_t)i * 256;
    float acc = row[lane] * c[lane] + row[lane + 64] * c[lane + 64]
              + row[lane + 128] * c[lane + 128] + row[lane + 192] * c[lane + 192];
    #pragma unroll
    for (int off = 32; off; off >>= 1) acc += __shfl_down(acc, off, 64);
    if (lane == 0) s[b * 512 + i] = acc * LIN_SCALE + sb[i];
  }
}

// ---------------- 2. demod[b][o] + base bf16 weight Wb[tap][o][i] ----------------
__global__ __launch_bounds__(256) void demod_kernel(const float* __restrict__ weight,
                                                    const float* __restrict__ s,
                                                    float* __restrict__ demod,
                                                    unsigned short* __restrict__ Wb) {
  const int o = blockIdx.x;
  const int tid = threadIdx.x;
  __shared__ float wsh[1536];        // weight[o][:][:]
  __shared__ float svs[16 * 512];    // all style vectors (32 KB)
  __shared__ float partial[16][4];

  #pragma unroll
  for (int j = tid; j < 384; j += 256)
    ((float4*)wsh)[j] = ((const float4*)(weight + (size_t)o * 1536))[j];
  #pragma unroll
  for (int j = tid; j < 2048; j += 256)
    ((float4*)svs)[j] = ((const float4*)s)[j];
  __syncthreads();

  float wr[6];
  #pragma unroll
  for (int q = 0; q < 6; ++q) wr[q] = wsh[tid * 6 + q] * CONV_SCALE;

  // batch-independent bf16 base weight: Wb[k][o][i], i = 2*tid, 2*tid+1
  #pragma unroll
  for (int k = 0; k < 3; ++k) {
    u16x2 v;
    v.x = f2bf(wr[k]);
    v.y = f2bf(wr[3 + k]);
    *(u16x2*)&Wb[((size_t)(k * 512 + o)) * 512 + 2 * tid] = v;
  }

  const int lane = tid & 63, w = tid >> 6;
  float ssb[16];
  #pragma unroll
  for (int b = 0; b < 16; ++b) {
    const float s0 = svs[b * 512 + 2 * tid];
    const float s1 = svs[b * 512 + 2 * tid + 1];
    float ss = 0.f;
    #pragma unroll
    for (int q = 0; q < 3; ++q) { float v = wr[q] * s0; ss += v * v; }
    #pragma unroll
    for (int q = 3; q < 6; ++q) { float v = wr[q] * s1; ss += v * v; }
    ssb[b] = ss;
  }
  #pragma unroll
  for (int b = 0; b < 16; ++b) {
    float ss = ssb[b];
    #pragma unroll
    for (int off = 32; off; off >>= 1) ss += __shfl_down(ss, off, 64);
    if (lane == 0) partial[b][w] = ss;
  }
  __syncthreads();
  if (tid < 16)
    demod[(size_t)tid * 512 + o] =
        rsqrtf(partial[tid][0] + partial[tid][1] + partial[tid][2] + partial[tid][3] + 1e-8f);
}

// ---------------- 3. transpose + pad + s-modulate + bf16 ----------------
__global__ __launch_bounds__(256) void transpose_kernel(const float* __restrict__ x,
                                                        const float* __restrict__ s,
                                                        unsigned short* __restrict__ xT) {
  __shared__ float tile[64][65];
  __shared__ float ss[64];
  const int b = blockIdx.z, i0 = blockIdx.y * 64, t0 = blockIdx.x * 64;
  const int tid = threadIdx.x;

  if (tid < 64) ss[tid] = s[(size_t)b * 512 + i0 + tid];

  const int lr = tid >> 4;            // 0..15
  const int lc = (tid & 15) * 4;      // float4
  const float* xb = x + ((size_t)b * CIN + i0) * T_ + t0;
  #pragma unroll
  for (int p = 0; p < 4; ++p) {
    const int r = p * 16 + lr;
    const float4 v = *(const float4*)(xb + (size_t)r * T_ + lc);
    tile[r][lc + 0] = v.x; tile[r][lc + 1] = v.y;
    tile[r][lc + 2] = v.z; tile[r][lc + 3] = v.w;
  }
  // fused zero-pad of rows 0 and 2049 (no barrier dependency)
  if (blockIdx.x == 0 && tid < 8)
    *(u16x8*)&xT[(size_t)b * TP * CIN + i0 + tid * 8] = (u16x8){0,0,0,0,0,0,0,0};
  if (blockIdx.x == gridDim.x - 1 && tid < 8)
    *(u16x8*)&xT[((size_t)b * TP + TP - 1) * CIN + i0 + tid * 8] = (u16x8){0,0,0,0,0,0,0,0};
  __syncthreads();

  const int st = tid >> 3;            // 0..31
  const int si = (tid & 7) * 8;       // 16B
  float sv[8];
  #pragma unroll
  for (int q = 0; q < 8; ++q) sv[q] = ss[si + q];
  unsigned short* xTb = xT + ((size_t)b * TP + 1 + t0) * CIN + i0;
  #pragma unroll
  for (int p = 0; p < 2; ++p) {
    const int t = p * 32 + st;
    u16x8 v;
    #pragma unroll
    for (int q = 0; q < 8; ++q) v[q] = f2bf(tile[si + q][t] * sv[q]);
    *(u16x8*)&xTb[(size_t)t * CIN + si] = v;
  }
}

// ---------------- 4. main GEMM: minimum 2-phase, dbuf LDS, 1 barrier/K-step ----------------
// out[b][o0..+128][t0..+512] = demod[b][o] * sum_{tap,i} Wb[tap][o][i] * xT[b][t0+lt+tap][i]
// lA[2][(tap*128+ar)*4+c][8], lB[2][(row)*4+c][8]; chunk-swizzle c^((row>>1)&3).
#define VMCNT0  asm volatile("s_waitcnt vmcnt(0)" ::: "memory")

#define STAGEB(buf, i0g) do {                                                 \
    _Pragma("unroll")                                                         \
    for (int q = 0; q < 4; ++q) {                                             \
      const int ci  = q * 512 + tid;                                          \
      const int row = ci >> 2;                                                \
      const int gc  = ((ci & 3) ^ ((row >> 1) & 3)) * 8;                      \
      __builtin_amdgcn_global_load_lds(                                       \
          (const AS1 void*)(gX + (size_t)row * CIN + (i0g) + gc),             \
          (AS3 void*)(&lB[buf][ci * 8]), 16, 0, 0);                           \
    }                                                                         \
    if (tid < 8) {                                                            \
      const int ci  = 2048 + tid;                                             \
      const int row = ci >> 2;             /* 512..513 */                     \
      const int gc  = ((ci & 3) ^ ((row >> 1) & 3)) * 8;                      \
      __builtin_amdgcn_global_load_lds(                                       \
          (const AS1 void*)(gX + (size_t)row * CIN + (i0g) + gc),             \
          (AS3 void*)(&lB[buf][ci * 8]), 16, 0, 0);                           \
    } } while (0)

#define STAGEA(buf, i0g) do {                                                 \
    _Pragma("unroll")                                                         \
    for (int q = 0; q < 3; ++q) {                                             \
      const int ci  = q * 512 + tid;                                          \
      const int row = ci >> 2;             /* tap*128 + ar */                 \
      const int tap = row >> 7;                                               \
      const int ar  = row & 127;                                              \
      const int gc  = ((ci & 3) ^ ((ar >> 1) & 3)) * 8;                       \
      __builtin_amdgcn_global_load_lds(                                       \
          (const AS1 void*)(gW + (size_t)tap * 262144 + (size_t)ar * 512 + (i0g) + gc), \
          (AS3 void*)(&lA[buf][ci * 8]), 16, 0, 0);                           \
    } } while (0)

__global__ __launch_bounds__(512, 2) void gemm_kernel(const unsigned short* __restrict__ Wb,
                                                      const unsigned short* __restrict__ xT,
                                                      const float* __restrict__ demod,
                                                      float* __restrict__ out) {
  __shared__ unsigned short lA[2][1536 * 8];   // 2 x 24576 B
  __shared__ unsigned short lB[2][2056 * 8];   // 2 x 32896 B  (rows 0..513)

  // XCD b-grouping: 256 blocks; id==xcd (mod 8); 2 batches per XCD.
  const int id  = blockIdx.x;
  const int xcd = id & 7;
  const int j   = id >> 3;                 // 0..31
  const int b   = xcd + 8 * (j >> 4);      // 0..15
  const int r   = j & 15;
  const int o0  = (r >> 2) * 128;          // 4 o-blocks
  const int t0  = (r & 3) * 512;           // 4 t-blocks

  const int tid  = threadIdx.x;
  const int lane = tid & 63;
  const int wid  = tid >> 6;               // 0..7
  const int wm   = (wid & 1) * 64;         // 2 M(o)-waves
  const int wn   = (wid >> 1) * 128;       // 4 N(t)-waves
  const int rl   = lane & 15;
  const int kc   = lane >> 4;              // k-chunk 0..3

  const unsigned short* gW = Wb + (size_t)o0 * 512;            // batch-independent
  const unsigned short* gX = xT + ((size_t)b * TP + t0) * CIN;

  f32x4 acc[4][8];
  #pragma unroll
  for (int i = 0; i < 4; ++i)
    #pragma unroll
    for (int jj = 0; jj < 8; ++jj) acc[i][jj] = (f32x4){0.f, 0.f, 0.f, 0.f};

  // prologue: stage K-step 0 into buf 0, full drain
  STAGEB(0, 0);
  STAGEA(0, 0);
  VMCNT0;
  __builtin_amdgcn_s_barrier();

  for (int kk = 0; kk < 16; ++kk) {
    const int cur = kk & 1;
    // phase 1: issue next tile's staging FIRST (latency hidden under MFMAs)
    if (kk < 15) {
      STAGEB(cur ^ 1, (kk + 1) * 32);
      STAGEA(cur ^ 1, (kk + 1) * 32);
    }
    // phase 2: compute current tile
    #pragma unroll
    for (int tap = 0; tap < 3; ++tap) {
      bf16x8 af[4], bfr[8];
      #pragma unroll
      for (int mi = 0; mi < 4; ++mi) {
        const int ra = wm + mi * 16 + rl;
        af[mi] = *(const bf16x8*)&lA[cur][((tap * 128 + ra) * 4 + (kc ^ ((ra >> 1) & 3))) * 8];
      }
      #pragma unroll
      for (int ni = 0; ni < 8; ++ni) {
        const int rb = wn + ni * 16 + rl + tap;
        bfr[ni] = *(const bf16x8*)&lB[cur][(rb * 4 + (kc ^ ((rb >> 1) & 3))) * 8];
      }
      __builtin_amdgcn_s_setprio(1);
      #pragma unroll
      for (int mi = 0; mi < 4; ++mi)
        #pragma unroll
        for (int ni = 0; ni < 8; ++ni)
          acc[mi][ni] = __builtin_amdgcn_mfma_f32_16x16x32_bf16(af[mi], bfr[ni], acc[mi][ni], 0, 0, 0);
      __builtin_amdgcn_s_setprio(0);
    }
    // one drain + one barrier per K-step (loads were covered by ~3700cyc MFMA)
    VMCNT0;
    __builtin_amdgcn_s_barrier();
  }

  // epilogue: D row = (lane>>4)*4 + reg, col = lane&15 (m89 mapping); x demod
  float* ob = out + ((size_t)b * COUT + o0 + wm) * T_ + t0 + wn;
  const float* dm = demod + (size_t)b * 512 + o0 + wm;
  const int rrow = (lane >> 4) * 4;
  const int ccol = lane & 15;
  #pragma unroll
  for (int mi = 0; mi < 4; ++mi) {
    float dr[4];
    #pragma unroll
    for (int rr = 0; rr < 4; ++rr) dr[rr] = dm[mi * 16 + rrow + rr];
    #pragma unroll
    for (int ni = 0; ni < 8; ++ni)
      #pragma unroll
      for (int rr = 0; rr < 4; ++rr)
        ob[(size_t)(mi * 16 + rrow + rr) * T_ + ni * 16 + ccol] = acc[mi][ni][rr] * dr[rr];
  }
}

// ---------------------------------------------------------------------------
extern "C" void kernel_launch(void* const* d_in, const int* in_sizes, int n_in,
                              void* d_out, int out_size, void* d_ws, size_t ws_size,
                              hipStream_t stream) {
  const float* x       = (const float*)d_in[0];   // [16,512,2048]
  const float* c_src   = (const float*)d_in[1];   // [16,128]
  const float* c_trg   = (const float*)d_in[2];   // [16,128]
  const float* style_w = (const float*)d_in[3];   // [512,256]
  const float* style_b = (const float*)d_in[4];   // [512]
  const float* weight  = (const float*)d_in[5];   // [1,512,512,3]
  float* out = (float*)d_out;

  // workspace: s fp32 [16][512] @0; demod fp32 [16][512] @32768;
  //            Wb bf16 [3][512][512] @65536; xT bf16 [16][2050][512] @1638400
  char* ws = (char*)d_ws;
  float* s_buf          = (float*)ws;
  float* demod_buf      = (float*)(ws + 32768);
  unsigned short* Wb    = (unsigned short*)(ws + 65536);
  unsigned short* xTbuf = (unsigned short*)(ws + 65536 + 1572864);

  style_kernel<<<dim3(8, 16), 256, 0, stream>>>(c_src, c_trg, style_w, style_b, s_buf);
  demod_kernel<<<dim3(COUT), 256, 0, stream>>>(weight, s_buf, demod_buf, Wb);
  transpose_kernel<<<dim3(T_ / 64, CIN / 64, B_), 256, 0, stream>>>(x, s_buf, xTbuf);
  gemm_kernel<<<dim3(256), 512, 0, stream>>>(Wb, xTbuf, demod_buf, out);
}

// Round 6
// 186.733 us; speedup vs baseline: 1.9066x; 1.0009x over previous
//
#include <hip/hip_runtime.h>
#include <cstdint>
#include <cstddef>

// ---------------------------------------------------------------------------
// Style2ResidualBlock1DSrc: modulated conv1d (StyleGAN2-style) on MI355X.
// R9: occupancy/independence attack on the gemm.
//  Evidence: every 1-block/CU schedule (R5 3-phase, R8 2-phase) = 62us with
//  MfmaUtil 33% (= pure-MFMA floor 20.5us running unfed 2/3 of the time);
//  R4's 2 independent blocks/CU = 54-58us. LDS(3460cyc) and MFMA(3400cyc)
//  pipes serialize under lockstep barriers; independent blocks overlap them.
//  R4's occupancy was grid-capped (512 blocks = exactly 2/CU), not LDS-capped.
//  - gemm: 128-thr blocks (2 waves), block tile 128o x 128t, wave 64x128
//    (same verified frag math / swizzle / 2-barrier loop as R4), LDS 32.9KB,
//    grid 1024 -> 4 independent blocks/CU = 8 waves/CU in 4 barrier domains.
//  - setprio(1) around MFMA cluster: cross-block role diversity exists here
//    (m190's null was lockstep blocks).
// Prep kernels: R4 verbatim. Factorization kept: A = bf16 Wb[3][512][512]
// L2-resident, s folded into xT, demod in fp32 epilogue.
// ---------------------------------------------------------------------------

#define LIN_SCALE  0.0625f           // 1/sqrt(256)
#define CONV_SCALE 0.014731391f      // 1/sqrt(512*9)

#define B_   16
#define CIN  512
#define COUT 512
#define T_   2048
#define TP   2050                    // T + 2 pad rows

typedef __bf16 bf16x8 __attribute__((ext_vector_type(8)));
typedef float  f32x4  __attribute__((ext_vector_type(4)));
typedef unsigned short u16x8 __attribute__((ext_vector_type(8)));
typedef unsigned short u16x2 __attribute__((ext_vector_type(2)));

#define AS1 __attribute__((address_space(1)))
#define AS3 __attribute__((address_space(3)))

__device__ inline unsigned short f2bf(float f) {
  __bf16 h = (__bf16)f;              // RNE fptrunc
  return __builtin_bit_cast(unsigned short, h);
}

// ---------------- 1. style linear: s[b][i] ----------------
__global__ __launch_bounds__(256) void style_kernel(const float* __restrict__ c_src,
                                                    const float* __restrict__ c_trg,
                                                    const float* __restrict__ sw,
                                                    const float* __restrict__ sb,
                                                    float* __restrict__ s) {
  __shared__ float c[256];
  const int b = blockIdx.y;
  const int tid = threadIdx.x;
  c[tid] = (tid < 128) ? c_src[b * 128 + tid] : c_trg[b * 128 + tid - 128];
  __syncthreads();
  const int w = tid >> 6, lane = tid & 63;
  #pragma unroll
  for (int rr = 0; rr < 16; ++rr) {
    const int i = blockIdx.x * 64 + w * 16 + rr;
    const float* row = sw + (size_t)i * 256;
    float acc = row[lane] * c[lane] + row[lane + 64] * c[lane + 64]
              + row[lane + 128] * c[lane + 128] + row[lane + 192] * c[lane + 192];
    #pragma unroll
    for (int off = 32; off; off >>= 1) acc += __shfl_down(acc, off, 64);
    if (lane == 0) s[b * 512 + i] = acc * LIN_SCALE + sb[i];
  }
}

// ---------------- 2. demod[b][o] + base bf16 weight Wb[tap][o][i] ----------------
__global__ __launch_bounds__(256) void demod_kernel(const float* __restrict__ weight,
                                                    const float* __restrict__ s,
                                                    float* __restrict__ demod,
                                                    unsigned short* __restrict__ Wb) {
  const int o = blockIdx.x;
  const int tid = threadIdx.x;
  __shared__ float wsh[1536];        // weight[o][:][:]
  __shared__ float svs[16 * 512];    // all style vectors (32 KB)
  __shared__ float partial[16][4];

  #pragma unroll
  for (int j = tid; j < 384; j += 256)
    ((float4*)wsh)[j] = ((const float4*)(weight + (size_t)o * 1536))[j];
  #pragma unroll
  for (int j = tid; j < 2048; j += 256)
    ((float4*)svs)[j] = ((const float4*)s)[j];
  __syncthreads();

  float wr[6];
  #pragma unroll
  for (int q = 0; q < 6; ++q) wr[q] = wsh[tid * 6 + q] * CONV_SCALE;

  // batch-independent bf16 base weight: Wb[k][o][i], i = 2*tid, 2*tid+1
  #pragma unroll
  for (int k = 0; k < 3; ++k) {
    u16x2 v;
    v.x = f2bf(wr[k]);
    v.y = f2bf(wr[3 + k]);
    *(u16x2*)&Wb[((size_t)(k * 512 + o)) * 512 + 2 * tid] = v;
  }

  const int lane = tid & 63, w = tid >> 6;
  float ssb[16];
  #pragma unroll
  for (int b = 0; b < 16; ++b) {
    const float s0 = svs[b * 512 + 2 * tid];
    const float s1 = svs[b * 512 + 2 * tid + 1];
    float ss = 0.f;
    #pragma unroll
    for (int q = 0; q < 3; ++q) { float v = wr[q] * s0; ss += v * v; }
    #pragma unroll
    for (int q = 3; q < 6; ++q) { float v = wr[q] * s1; ss += v * v; }
    ssb[b] = ss;
  }
  #pragma unroll
  for (int b = 0; b < 16; ++b) {
    float ss = ssb[b];
    #pragma unroll
    for (int off = 32; off; off >>= 1) ss += __shfl_down(ss, off, 64);
    if (lane == 0) partial[b][w] = ss;
  }
  __syncthreads();
  if (tid < 16)
    demod[(size_t)tid * 512 + o] =
        rsqrtf(partial[tid][0] + partial[tid][1] + partial[tid][2] + partial[tid][3] + 1e-8f);
}

// ---------------- 3. transpose + pad + s-modulate + bf16 ----------------
__global__ __launch_bounds__(256) void transpose_kernel(const float* __restrict__ x,
                                                        const float* __restrict__ s,
                                                        unsigned short* __restrict__ xT) {
  __shared__ float tile[64][65];
  __shared__ float ss[64];
  const int b = blockIdx.z, i0 = blockIdx.y * 64, t0 = blockIdx.x * 64;
  const int tid = threadIdx.x;

  if (tid < 64) ss[tid] = s[(size_t)b * 512 + i0 + tid];

  const int lr = tid >> 4;            // 0..15
  const int lc = (tid & 15) * 4;      // float4
  const float* xb = x + ((size_t)b * CIN + i0) * T_ + t0;
  #pragma unroll
  for (int p = 0; p < 4; ++p) {
    const int r = p * 16 + lr;
    const float4 v = *(const float4*)(xb + (size_t)r * T_ + lc);
    tile[r][lc + 0] = v.x; tile[r][lc + 1] = v.y;
    tile[r][lc + 2] = v.z; tile[r][lc + 3] = v.w;
  }
  // fused zero-pad of rows 0 and 2049 (no barrier dependency)
  if (blockIdx.x == 0 && tid < 8)
    *(u16x8*)&xT[(size_t)b * TP * CIN + i0 + tid * 8] = (u16x8){0,0,0,0,0,0,0,0};
  if (blockIdx.x == gridDim.x - 1 && tid < 8)
    *(u16x8*)&xT[((size_t)b * TP + TP - 1) * CIN + i0 + tid * 8] = (u16x8){0,0,0,0,0,0,0,0};
  __syncthreads();

  const int st = tid >> 3;            // 0..31
  const int si = (tid & 7) * 8;       // 16B
  float sv[8];
  #pragma unroll
  for (int q = 0; q < 8; ++q) sv[q] = ss[si + q];
  unsigned short* xTb = xT + ((size_t)b * TP + 1 + t0) * CIN + i0;
  #pragma unroll
  for (int p = 0; p < 2; ++p) {
    const int t = p * 32 + st;
    u16x8 v;
    #pragma unroll
    for (int q = 0; q < 8; ++q) v[q] = f2bf(tile[si + q][t] * sv[q]);
    *(u16x8*)&xTb[(size_t)t * CIN + si] = v;
  }
}

// ---------------- 4. main GEMM: 128-thr blocks, 4 independent blocks/CU ----------------
// out[b][o0..+128][t0..+128] = demod[b][o] * sum_{tap,i} Wb[tap][o][i] * xT[b][t0+lt+tap][i]
// 2 waves (M-split): wave tile 64(o) x 128(t) = 4x8 16x16x32 frags.
// LDS: lA[3][128][32] (24576B) + lB[130][32] (8320B) = 32.9KB -> 4 blocks/CU.
// R4's 2-barrier loop; chunk swizzle c^((row>>1)&3) on both operands.
__global__ __launch_bounds__(128, 2) void gemm_kernel(const unsigned short* __restrict__ Wb,
                                                      const unsigned short* __restrict__ xT,
                                                      const float* __restrict__ demod,
                                                      float* __restrict__ out) {
  __shared__ unsigned short lA[1536 * 8];   // 24576 B
  __shared__ unsigned short lB[520 * 8];    // 8320 B (rows 0..129)

  // XCD b-grouping: 1024 blocks; id==xcd (mod 8); 2 batches per XCD.
  const int id  = blockIdx.x;
  const int xcd = id & 7;
  const int j   = id >> 3;                 // 0..127
  const int b   = xcd + 8 * (j >> 6);      // 0..15
  const int r   = j & 63;
  const int o0  = (r >> 4) * 128;          // 4 o-blocks
  const int t0  = (r & 15) * 128;          // 16 t-blocks

  const int tid  = threadIdx.x;
  const int lane = tid & 63;
  const int wm   = (tid >> 6) * 64;        // 2 M(o)-waves
  const int rl   = lane & 15;
  const int kc   = lane >> 4;              // k-chunk 0..3

  const unsigned short* gW = Wb + (size_t)o0 * 512;            // batch-independent
  const unsigned short* gX = xT + ((size_t)b * TP + t0) * CIN;

  f32x4 acc[4][8];
  #pragma unroll
  for (int i = 0; i < 4; ++i)
    #pragma unroll
    for (int jj = 0; jj < 8; ++jj) acc[i][jj] = (f32x4){0.f, 0.f, 0.f, 0.f};

  for (int kk = 0; kk < 16; ++kk) {
    const int i0 = kk * 32;
    __syncthreads();                       // previous compute done
    // A: 1536 16B-chunks, 12 per thread. chunk ci=(tap*128+ar)*4+c
    #pragma unroll
    for (int q = 0; q < 12; ++q) {
      const int ci  = q * 128 + tid;
      const int row = ci >> 2;             // tap*128 + ar
      const int tap = row >> 7;
      const int ar  = row & 127;
      const int gc  = ((ci & 3) ^ ((ar >> 1) & 3)) * 8;
      __builtin_amdgcn_global_load_lds(
          (const AS1 void*)(gW + (size_t)tap * 262144 + (size_t)ar * 512 + i0 + gc),
          (AS3 void*)(&lA[ci * 8]), 16, 0, 0);
    }
    // B: 130 rows x 4 chunks = 520; 4 per thread + tail 8
    #pragma unroll
    for (int q = 0; q < 4; ++q) {
      const int ci  = q * 128 + tid;
      const int row = ci >> 2;
      const int gc  = ((ci & 3) ^ ((row >> 1) & 3)) * 8;
      __builtin_amdgcn_global_load_lds(
          (const AS1 void*)(gX + (size_t)row * CIN + i0 + gc),
          (AS3 void*)(&lB[ci * 8]), 16, 0, 0);
    }
    if (tid < 8) {
      const int ci  = 512 + tid;
      const int row = ci >> 2;             // 128, 129
      const int gc  = ((ci & 3) ^ ((row >> 1) & 3)) * 8;
      __builtin_amdgcn_global_load_lds(
          (const AS1 void*)(gX + (size_t)row * CIN + i0 + gc),
          (AS3 void*)(&lB[ci * 8]), 16, 0, 0);
    }
    __syncthreads();                       // staging visible

    #pragma unroll
    for (int tap = 0; tap < 3; ++tap) {
      bf16x8 af[4], bfr[8];
      #pragma unroll
      for (int mi = 0; mi < 4; ++mi) {
        const int ra = wm + mi * 16 + rl;
        af[mi] = *(const bf16x8*)&lA[((tap * 128 + ra) * 4 + (kc ^ ((ra >> 1) & 3))) * 8];
      }
      #pragma unroll
      for (int ni = 0; ni < 8; ++ni) {
        const int rb = ni * 16 + rl + tap;
        bfr[ni] = *(const bf16x8*)&lB[(rb * 4 + (kc ^ ((rb >> 1) & 3))) * 8];
      }
      __builtin_amdgcn_s_setprio(1);
      #pragma unroll
      for (int mi = 0; mi < 4; ++mi)
        #pragma unroll
        for (int ni = 0; ni < 8; ++ni)
          acc[mi][ni] = __builtin_amdgcn_mfma_f32_16x16x32_bf16(af[mi], bfr[ni], acc[mi][ni], 0, 0, 0);
      __builtin_amdgcn_s_setprio(0);
    }
  }

  // epilogue: D row = (lane>>4)*4 + reg, col = lane&15 (m89 mapping); x demod
  float* ob = out + ((size_t)b * COUT + o0 + wm) * T_ + t0;
  const float* dm = demod + (size_t)b * 512 + o0 + wm;
  const int rrow = (lane >> 4) * 4;
  const int ccol = lane & 15;
  #pragma unroll
  for (int mi = 0; mi < 4; ++mi) {
    float dr[4];
    #pragma unroll
    for (int rr = 0; rr < 4; ++rr) dr[rr] = dm[mi * 16 + rrow + rr];
    #pragma unroll
    for (int ni = 0; ni < 8; ++ni)
      #pragma unroll
      for (int rr = 0; rr < 4; ++rr)
        ob[(size_t)(mi * 16 + rrow + rr) * T_ + ni * 16 + ccol] = acc[mi][ni][rr] * dr[rr];
  }
}

// ---------------------------------------------------------------------------
extern "C" void kernel_launch(void* const* d_in, const int* in_sizes, int n_in,
                              void* d_out, int out_size, void* d_ws, size_t ws_size,
                              hipStream_t stream) {
  const float* x       = (const float*)d_in[0];   // [16,512,2048]
  const float* c_src   = (const float*)d_in[1];   // [16,128]
  const float* c_trg   = (const float*)d_in[2];   // [16,128]
  const float* style_w = (const float*)d_in[3];   // [512,256]
  const float* style_b = (const float*)d_in[4];   // [512]
  const float* weight  = (const float*)d_in[5];   // [1,512,512,3]
  float* out = (float*)d_out;

  // workspace: s fp32 [16][512] @0; demod fp32 [16][512] @32768;
  //            Wb bf16 [3][512][512] @65536; xT bf16 [16][2050][512] @1638400
  char* ws = (char*)d_ws;
  float* s_buf          = (float*)ws;
  float* demod_buf      = (float*)(ws + 32768);
  unsigned short* Wb    = (unsigned short*)(ws + 65536);
  unsigned short* xTbuf = (unsigned short*)(ws + 65536 + 1572864);

  style_kernel<<<dim3(8, 16), 256, 0, stream>>>(c_src, c_trg, style_w, style_b, s_buf);
  demod_kernel<<<dim3(COUT), 256, 0, stream>>>(weight, s_buf, demod_buf, Wb);
  transpose_kernel<<<dim3(T_ / 64, CIN / 64, B_), 256, 0, stream>>>(x, s_buf, xTbuf);
  gemm_kernel<<<dim3(1024), 128, 0, stream>>>(Wb, xTbuf, demod_buf, out);
}

// Round 9
// 184.647 us; speedup vs baseline: 1.9282x; 1.0113x over previous
//
#include <hip/hip_runtime.h>
#include <cstdint>
#include <cstddef>

// ---------------------------------------------------------------------------
// Style2ResidualBlock1DSrc: modulated conv1d (StyleGAN2-style) on MI355X.
// R11 (safe closer after 2 container failures on the R10 8-phase port):
//  - Prep kernels: R4 verbatim (passed, measured).
//  - Gemm: R4's verified 2-barrier staging structure verbatim + R7's verified
//    operand swap (D = mfma(xT_frag, Wb_frag)) so D-rows = t:
//      * float4 epilogue stores (32x16B vs 128 scalar), demod 4 loads/thread.
//      * A stays LDS-staged (R7's regression was its scattered L2 A-gather,
//        NOT the swap; that path is not carried over).
//  Every component individually harness-verified (passed, absmax 0.03125).
// Factorization kept: A = bf16 Wb[3][512][512] (L2-resident), s folded into
// xT at transpose time, demod applied in fp32 epilogue.
// ---------------------------------------------------------------------------

#define LIN_SCALE  0.0625f           // 1/sqrt(256)
#define CONV_SCALE 0.014731391f      // 1/sqrt(512*9)

#define B_   16
#define CIN  512
#define COUT 512
#define T_   2048
#define TP   2050                    // T + 2 pad rows

typedef __bf16 bf16x8 __attribute__((ext_vector_type(8)));
typedef float  f32x4  __attribute__((ext_vector_type(4)));
typedef unsigned short u16x8 __attribute__((ext_vector_type(8)));
typedef unsigned short u16x2 __attribute__((ext_vector_type(2)));

#define AS1 __attribute__((address_space(1)))
#define AS3 __attribute__((address_space(3)))

__device__ inline unsigned short f2bf(float f) {
  __bf16 h = (__bf16)f;              // RNE fptrunc
  return __builtin_bit_cast(unsigned short, h);
}

// ---------------- 1. style linear: s[b][i] ----------------
__global__ __launch_bounds__(256) void style_kernel(const float* __restrict__ c_src,
                                                    const float* __restrict__ c_trg,
                                                    const float* __restrict__ sw,
                                                    const float* __restrict__ sb,
                                                    float* __restrict__ s) {
  __shared__ float c[256];
  const int b = blockIdx.y;
  const int tid = threadIdx.x;
  c[tid] = (tid < 128) ? c_src[b * 128 + tid] : c_trg[b * 128 + tid - 128];
  __syncthreads();
  const int w = tid >> 6, lane = tid & 63;
  #pragma unroll
  for (int rr = 0; rr < 16; ++rr) {
    const int i = blockIdx.x * 64 + w * 16 + rr;
    const float* row = sw + (size_t)i * 256;
    float acc = row[lane] * c[lane] + row[lane + 64] * c[lane + 64]
              + row[lane + 128] * c[lane + 128] + row[lane + 192] * c[lane + 192];
    #pragma unroll
    for (int off = 32; off; off >>= 1) acc += __shfl_down(acc, off, 64);
    if (lane == 0) s[b * 512 + i] = acc * LIN_SCALE + sb[i];
  }
}

// ---------------- 2. demod[b][o] + base bf16 weight Wb[tap][o][i] ----------------
__global__ __launch_bounds__(256) void demod_kernel(const float* __restrict__ weight,
                                                    const float* __restrict__ s,
                                                    float* __restrict__ demod,
                                                    unsigned short* __restrict__ Wb) {
  const int o = blockIdx.x;
  const int tid = threadIdx.x;
  __shared__ float wsh[1536];        // weight[o][:][:]
  __shared__ float svs[16 * 512];    // all style vectors (32 KB)
  __shared__ float partial[16][4];

  #pragma unroll
  for (int j = tid; j < 384; j += 256)
    ((float4*)wsh)[j] = ((const float4*)(weight + (size_t)o * 1536))[j];
  #pragma unroll
  for (int j = tid; j < 2048; j += 256)
    ((float4*)svs)[j] = ((const float4*)s)[j];
  __syncthreads();

  float wr[6];
  #pragma unroll
  for (int q = 0; q < 6; ++q) wr[q] = wsh[tid * 6 + q] * CONV_SCALE;

  // batch-independent bf16 base weight: Wb[k][o][i], i = 2*tid, 2*tid+1
  #pragma unroll
  for (int k = 0; k < 3; ++k) {
    u16x2 v;
    v.x = f2bf(wr[k]);
    v.y = f2bf(wr[3 + k]);
    *(u16x2*)&Wb[((size_t)(k * 512 + o)) * 512 + 2 * tid] = v;
  }

  const int lane = tid & 63, w = tid >> 6;
  float ssb[16];
  #pragma unroll
  for (int b = 0; b < 16; ++b) {
    const float s0 = svs[b * 512 + 2 * tid];
    const float s1 = svs[b * 512 + 2 * tid + 1];
    float ss = 0.f;
    #pragma unroll
    for (int q = 0; q < 3; ++q) { float v = wr[q] * s0; ss += v * v; }
    #pragma unroll
    for (int q = 3; q < 6; ++q) { float v = wr[q] * s1; ss += v * v; }
    ssb[b] = ss;
  }
  #pragma unroll
  for (int b = 0; b < 16; ++b) {
    float ss = ssb[b];
    #pragma unroll
    for (int off = 32; off; off >>= 1) ss += __shfl_down(ss, off, 64);
    if (lane == 0) partial[b][w] = ss;
  }
  __syncthreads();
  if (tid < 16)
    demod[(size_t)tid * 512 + o] =
        rsqrtf(partial[tid][0] + partial[tid][1] + partial[tid][2] + partial[tid][3] + 1e-8f);
}

// ---------------- 3. transpose + pad + s-modulate + bf16 ----------------
__global__ __launch_bounds__(256) void transpose_kernel(const float* __restrict__ x,
                                                        const float* __restrict__ s,
                                                        unsigned short* __restrict__ xT) {
  __shared__ float tile[64][65];
  __shared__ float ss[64];
  const int b = blockIdx.z, i0 = blockIdx.y * 64, t0 = blockIdx.x * 64;
  const int tid = threadIdx.x;

  if (tid < 64) ss[tid] = s[(size_t)b * 512 + i0 + tid];

  const int lr = tid >> 4;            // 0..15
  const int lc = (tid & 15) * 4;      // float4
  const float* xb = x + ((size_t)b * CIN + i0) * T_ + t0;
  #pragma unroll
  for (int p = 0; p < 4; ++p) {
    const int r = p * 16 + lr;
    const float4 v = *(const float4*)(xb + (size_t)r * T_ + lc);
    tile[r][lc + 0] = v.x; tile[r][lc + 1] = v.y;
    tile[r][lc + 2] = v.z; tile[r][lc + 3] = v.w;
  }
  // fused zero-pad of rows 0 and 2049 (no barrier dependency)
  if (blockIdx.x == 0 && tid < 8)
    *(u16x8*)&xT[(size_t)b * TP * CIN + i0 + tid * 8] = (u16x8){0,0,0,0,0,0,0,0};
  if (blockIdx.x == gridDim.x - 1 && tid < 8)
    *(u16x8*)&xT[((size_t)b * TP + TP - 1) * CIN + i0 + tid * 8] = (u16x8){0,0,0,0,0,0,0,0};
  __syncthreads();

  const int st = tid >> 3;            // 0..31
  const int si = (tid & 7) * 8;       // 16B
  float sv[8];
  #pragma unroll
  for (int q = 0; q < 8; ++q) sv[q] = ss[si + q];
  unsigned short* xTb = xT + ((size_t)b * TP + 1 + t0) * CIN + i0;
  #pragma unroll
  for (int p = 0; p < 2; ++p) {
    const int t = p * 32 + st;
    u16x8 v;
    #pragma unroll
    for (int q = 0; q < 8; ++q) v[q] = f2bf(tile[si + q][t] * sv[q]);
    *(u16x8*)&xTb[(size_t)t * CIN + si] = v;
  }
}

// ---------------- 4. main GEMM: R4 2-barrier structure, swapped operands ----------------
// out[b][o0+wm+ni*16+oc][t0+wn+mi*16+tr..+3] = demod * acc[mi][ni]
// acc = mfma(xT_frag (A-op, t rows), Wb_frag (B-op, o cols)) -> D rows = t.
// Staging identical to R4: lA[3][128][32], lB[258][32], chunk-swz c^((row>>1)&3).
__global__ __launch_bounds__(256, 2) void gemm_kernel(const unsigned short* __restrict__ Wb,
                                                      const unsigned short* __restrict__ xT,
                                                      const float* __restrict__ demod,
                                                      float* __restrict__ out) {
  __shared__ unsigned short lA[3 * 128 * 32];   // 24576 B
  __shared__ unsigned short lB[258 * 32];       // 16512 B

  // XCD b-grouping: 512 blocks; ids == xcd (mod 8); 2 batches per XCD.
  const int id  = blockIdx.x;
  const int xcd = id & 7;
  const int j   = id >> 3;                 // 0..63
  const int b   = xcd + 8 * (j >> 5);      // 0..15
  const int r   = j & 31;
  const int o0  = (r >> 3) * 128;          // 4 o-blocks
  const int t0  = (r & 7) * 256;           // 8 t-blocks

  const int tid  = threadIdx.x;
  const int lane = tid & 63;
  const int wm   = ((tid >> 6) & 1) * 64;  // wave o offset
  const int wn   = (tid >> 7) * 128;       // wave t offset
  const int rl   = lane & 15;
  const int kc   = lane >> 4;              // chunk 0..3 within 32-wide row

  const unsigned short* gW = Wb + (size_t)o0 * 512;            // batch-independent
  const unsigned short* gX = xT + ((size_t)b * TP + t0) * CIN;

  f32x4 acc[8][4];                         // [t-frag][o-frag]
  #pragma unroll
  for (int i = 0; i < 8; ++i)
    #pragma unroll
    for (int jj = 0; jj < 4; ++jj) acc[i][jj] = (f32x4){0.f, 0.f, 0.f, 0.f};

  for (int kk = 0; kk < 16; ++kk) {
    const int i0 = kk * 32;
    __syncthreads();                       // previous compute done
    // A: 1536 16B-chunks, 6 per thread. chunk ci=(tap*128+ar)*4+c
    #pragma unroll
    for (int q = 0; q < 6; ++q) {
      const int ci  = q * 256 + tid;
      const int row = ci >> 2;             // tap*128 + ar
      const int tap = row >> 7;
      const int ar  = row & 127;
      const int gc  = ((ci & 3) ^ ((ar >> 1) & 3)) * 8;
      __builtin_amdgcn_global_load_lds(
          (const AS1 void*)(gW + (size_t)tap * 262144 + (size_t)ar * 512 + i0 + gc),
          (AS3 void*)(&lA[ci * 8]), 16, 0, 0);
    }
    // B: 258 rows x 4 chunks = 1032; 4 per thread + tail 8
    #pragma unroll
    for (int q = 0; q < 4; ++q) {
      const int ci  = q * 256 + tid;
      const int row = ci >> 2;
      const int gc  = ((ci & 3) ^ ((row >> 1) & 3)) * 8;
      __builtin_amdgcn_global_load_lds(
          (const AS1 void*)(gX + (size_t)row * CIN + i0 + gc),
          (AS3 void*)(&lB[ci * 8]), 16, 0, 0);
    }
    if (tid < 8) {
      const int ci  = 1024 + tid;
      const int row = ci >> 2;             // 256, 257
      const int gc  = ((ci & 3) ^ ((row >> 1) & 3)) * 8;
      __builtin_amdgcn_global_load_lds(
          (const AS1 void*)(gX + (size_t)row * CIN + i0 + gc),
          (AS3 void*)(&lB[ci * 8]), 16, 0, 0);
    }
    __syncthreads();                       // staging visible

    #pragma unroll
    for (int tap = 0; tap < 3; ++tap) {
      bf16x8 wf[4], xf[8];
      #pragma unroll
      for (int ni = 0; ni < 4; ++ni) {
        const int ra = wm + ni * 16 + rl;
        wf[ni] = *(const bf16x8*)&lA[((tap * 128 + ra) * 4 + (kc ^ ((ra >> 1) & 3))) * 8];
      }
      #pragma unroll
      for (int mi = 0; mi < 8; ++mi) {
        const int rb = wn + mi * 16 + rl + tap;
        xf[mi] = *(const bf16x8*)&lB[(rb * 4 + (kc ^ ((rb >> 1) & 3))) * 8];
      }
      #pragma unroll
      for (int mi = 0; mi < 8; ++mi)
        #pragma unroll
        for (int ni = 0; ni < 4; ++ni)
          acc[mi][ni] = __builtin_amdgcn_mfma_f32_16x16x32_bf16(xf[mi], wf[ni], acc[mi][ni], 0, 0, 0);
    }
  }

  // epilogue (R7-verified): D col = lane&15 -> o; row = (lane>>4)*4+reg -> t
  const int ccol = lane & 15;
  const int trow = (lane >> 4) * 4;
  float dmv[4];
  #pragma unroll
  for (int ni = 0; ni < 4; ++ni)
    dmv[ni] = demod[(size_t)b * 512 + o0 + wm + ni * 16 + ccol];
  float* ob = out + ((size_t)b * COUT + o0 + wm + ccol) * T_ + t0 + wn + trow;
  #pragma unroll
  for (int mi = 0; mi < 8; ++mi)
    #pragma unroll
    for (int ni = 0; ni < 4; ++ni) {
      f32x4 v = acc[mi][ni];
      v.x *= dmv[ni]; v.y *= dmv[ni]; v.z *= dmv[ni]; v.w *= dmv[ni];
      *(f32x4*)&ob[(size_t)ni * 16 * T_ + mi * 16] = v;
    }
}

// ---------------------------------------------------------------------------
extern "C" void kernel_launch(void* const* d_in, const int* in_sizes, int n_in,
                              void* d_out, int out_size, void* d_ws, size_t ws_size,
                              hipStream_t stream) {
  const float* x       = (const float*)d_in[0];   // [16,512,2048]
  const float* c_src   = (const float*)d_in[1];   // [16,128]
  const float* c_trg   = (const float*)d_in[2];   // [16,128]
  const float* style_w = (const float*)d_in[3];   // [512,256]
  const float* style_b = (const float*)d_in[4];   // [512]
  const float* weight  = (const float*)d_in[5];   // [1,512,512,3]
  float* out = (float*)d_out;

  // workspace: s fp32 [16][512] @0; demod fp32 [16][512] @32768;
  //            Wb bf16 [3][512][512] @65536; xT bf16 [16][2050][512] @1638400
  char* ws = (char*)d_ws;
  float* s_buf          = (float*)ws;
  float* demod_buf      = (float*)(ws + 32768);
  unsigned short* Wb    = (unsigned short*)(ws + 65536);
  unsigned short* xTbuf = (unsigned short*)(ws + 65536 + 1572864);

  style_kernel<<<dim3(8, 16), 256, 0, stream>>>(c_src, c_trg, style_w, style_b, s_buf);
  demod_kernel<<<dim3(COUT), 256, 0, stream>>>(weight, s_buf, demod_buf, Wb);
  transpose_kernel<<<dim3(T_ / 64, CIN / 64, B_), 256, 0, stream>>>(x, s_buf, xTbuf);
  gemm_kernel<<<dim3(512), 256, 0, stream>>>(Wb, xTbuf, demod_buf, out);
}

// Round 10
// 179.695 us; speedup vs baseline: 1.9813x; 1.0276x over previous
//
#include <hip/hip_runtime.h>
#include <cstdint>
#include <cstddef>

// ---------------------------------------------------------------------------
// Style2ResidualBlock1DSrc: modulated conv1d (StyleGAN2-style) on MI355X.
// R12: dispatch-count attack (gemm frozen at R11's verified best).
//  Evidence: fixed overhead w/ 2 dispatches = 72us (R6); R11's 4-dispatch
//  prep+gaps = 55us vs ~28us kernel floors -> ~8-10us per launch gap.
//  - transpose & demod are mutually independent (both only read s) -> merged
//    into ONE flat-grid kernel (4096 transpose blocks + 512 demod blocks,
//    branch on blockIdx; no grid barrier, no occupancy pinning - the R6
//    fusion failure mode does not apply).
//  - demod path de-LDS'd: svs[16x512] stage dropped; 32 per-thread s values
//    read direct from L2 (identical FMA order -> bit-identical demod).
//    LDS union = transpose's 16.9KB -> 8 blocks/CU preserved.
//  - gemm: R11 verbatim (57.0-57.9us measured; 6 schedule variants all
//    54-62us = m97 ceiling; 8-phase escape killed 2 containers - frozen).
// Factorization kept: A = bf16 Wb[3][512][512] L2-resident, s folded into
// xT at transpose time, demod applied in fp32 epilogue.
// ---------------------------------------------------------------------------

#define LIN_SCALE  0.0625f           // 1/sqrt(256)
#define CONV_SCALE 0.014731391f      // 1/sqrt(512*9)

#define B_   16
#define CIN  512
#define COUT 512
#define T_   2048
#define TP   2050                    // T + 2 pad rows

typedef __bf16 bf16x8 __attribute__((ext_vector_type(8)));
typedef float  f32x4  __attribute__((ext_vector_type(4)));
typedef unsigned short u16x8 __attribute__((ext_vector_type(8)));
typedef unsigned short u16x2 __attribute__((ext_vector_type(2)));

#define AS1 __attribute__((address_space(1)))
#define AS3 __attribute__((address_space(3)))

__device__ inline unsigned short f2bf(float f) {
  __bf16 h = (__bf16)f;              // RNE fptrunc
  return __builtin_bit_cast(unsigned short, h);
}

// ---------------- 1. style linear: s[b][i] ----------------
__global__ __launch_bounds__(256) void style_kernel(const float* __restrict__ c_src,
                                                    const float* __restrict__ c_trg,
                                                    const float* __restrict__ sw,
                                                    const float* __restrict__ sb,
                                                    float* __restrict__ s) {
  __shared__ float c[256];
  const int b = blockIdx.y;
  const int tid = threadIdx.x;
  c[tid] = (tid < 128) ? c_src[b * 128 + tid] : c_trg[b * 128 + tid - 128];
  __syncthreads();
  const int w = tid >> 6, lane = tid & 63;
  #pragma unroll
  for (int rr = 0; rr < 16; ++rr) {
    const int i = blockIdx.x * 64 + w * 16 + rr;
    const float* row = sw + (size_t)i * 256;
    float acc = row[lane] * c[lane] + row[lane + 64] * c[lane + 64]
              + row[lane + 128] * c[lane + 128] + row[lane + 192] * c[lane + 192];
    #pragma unroll
    for (int off = 32; off; off >>= 1) acc += __shfl_down(acc, off, 64);
    if (lane == 0) s[b * 512 + i] = acc * LIN_SCALE + sb[i];
  }
}

// ---------------- 2. fused prep: transpose(4096 blocks) | demod(512 blocks) ----------------
// ids [0,4096): transpose+pad+s-modulate tile (R4 body verbatim, flat smem).
// ids [4096,4608): demod[b][o] + Wb row (svs-less: direct L2 s reads).
__global__ __launch_bounds__(256) void fused_prep_kernel(const float* __restrict__ x,
                                                         const float* __restrict__ s,
                                                         const float* __restrict__ weight,
                                                         unsigned short* __restrict__ xT,
                                                         float* __restrict__ demod,
                                                         unsigned short* __restrict__ Wb) {
  __shared__ __align__(16) char smem[16896];   // union: transpose 16896 | demod 6400
  const int id  = blockIdx.x;
  const int tid = threadIdx.x;

  if (id < 4096) {
    // ------------------ transpose path (verbatim R4 logic) ------------------
    float* tile = (float*)smem;                // [64][65]
    float* ss   = (float*)(smem + 16640);      // [64]
    const int t0 = (id & 31) * 64;
    const int i0 = ((id >> 5) & 7) * 64;
    const int b  = id >> 8;

    if (tid < 64) ss[tid] = s[(size_t)b * 512 + i0 + tid];

    const int lr = tid >> 4;            // 0..15
    const int lc = (tid & 15) * 4;      // float4
    const float* xb = x + ((size_t)b * CIN + i0) * T_ + t0;
    #pragma unroll
    for (int p = 0; p < 4; ++p) {
      const int r = p * 16 + lr;
      const float4 v = *(const float4*)(xb + (size_t)r * T_ + lc);
      tile[r * 65 + lc + 0] = v.x; tile[r * 65 + lc + 1] = v.y;
      tile[r * 65 + lc + 2] = v.z; tile[r * 65 + lc + 3] = v.w;
    }
    // fused zero-pad of rows 0 and 2049 (no barrier dependency)
    if (t0 == 0 && tid < 8)
      *(u16x8*)&xT[(size_t)b * TP * CIN + i0 + tid * 8] = (u16x8){0,0,0,0,0,0,0,0};
    if (t0 == T_ - 64 && tid < 8)
      *(u16x8*)&xT[((size_t)b * TP + TP - 1) * CIN + i0 + tid * 8] = (u16x8){0,0,0,0,0,0,0,0};
    __syncthreads();

    const int st = tid >> 3;            // 0..31
    const int si = (tid & 7) * 8;       // 16B
    float sv[8];
    #pragma unroll
    for (int q = 0; q < 8; ++q) sv[q] = ss[si + q];
    unsigned short* xTb = xT + ((size_t)b * TP + 1 + t0) * CIN + i0;
    #pragma unroll
    for (int p = 0; p < 2; ++p) {
      const int t = p * 32 + st;
      u16x8 v;
      #pragma unroll
      for (int q = 0; q < 8; ++q) v[q] = f2bf(tile[(si + q) * 65 + t] * sv[q]);
      *(u16x8*)&xTb[(size_t)t * CIN + si] = v;
    }
  } else {
    // ------------------ demod path (svs-less) ------------------
    const int o = id - 4096;
    float* wsh     = (float*)smem;             // 1536 floats
    float* partial = (float*)(smem + 6144);    // [16][4]

    #pragma unroll
    for (int j = tid; j < 384; j += 256)
      ((float4*)wsh)[j] = ((const float4*)(weight + (size_t)o * 1536))[j];
    __syncthreads();

    float wr[6];
    #pragma unroll
    for (int q = 0; q < 6; ++q) wr[q] = wsh[tid * 6 + q] * CONV_SCALE;

    // batch-independent bf16 base weight: Wb[k][o][i], i = 2*tid, 2*tid+1
    #pragma unroll
    for (int k = 0; k < 3; ++k) {
      u16x2 v;
      v.x = f2bf(wr[k]);
      v.y = f2bf(wr[3 + k]);
      *(u16x2*)&Wb[((size_t)(k * 512 + o)) * 512 + 2 * tid] = v;
    }

    // direct L2 s reads (s is 32KB, style-hot); identical FMA order to R4
    float s0v[16], s1v[16];
    #pragma unroll
    for (int b = 0; b < 16; ++b) {
      s0v[b] = s[b * 512 + 2 * tid];
      s1v[b] = s[b * 512 + 2 * tid + 1];
    }

    const int lane = tid & 63, w = tid >> 6;
    float ssb[16];
    #pragma unroll
    for (int b = 0; b < 16; ++b) {
      float ssq = 0.f;
      #pragma unroll
      for (int q = 0; q < 3; ++q) { float v = wr[q] * s0v[b]; ssq += v * v; }
      #pragma unroll
      for (int q = 3; q < 6; ++q) { float v = wr[q] * s1v[b]; ssq += v * v; }
      ssb[b] = ssq;
    }
    #pragma unroll
    for (int b = 0; b < 16; ++b) {
      float ssq = ssb[b];
      #pragma unroll
      for (int off = 32; off; off >>= 1) ssq += __shfl_down(ssq, off, 64);
      if (lane == 0) partial[b * 4 + w] = ssq;
    }
    __syncthreads();
    if (tid < 16)
      demod[(size_t)tid * 512 + o] =
          rsqrtf(partial[tid * 4] + partial[tid * 4 + 1] + partial[tid * 4 + 2]
               + partial[tid * 4 + 3] + 1e-8f);
  }
}

// ---------------- 3. main GEMM: R11 verbatim (2-barrier, swapped operands) ----------------
// out[b][o0+wm+ni*16+oc][t0+wn+mi*16+tr..+3] = demod * acc[mi][ni]
// acc = mfma(xT_frag (A-op, t rows), Wb_frag (B-op, o cols)) -> D rows = t.
// Staging: lA[3][128][32], lB[258][32], chunk-swz c^((row>>1)&3).
__global__ __launch_bounds__(256, 2) void gemm_kernel(const unsigned short* __restrict__ Wb,
                                                      const unsigned short* __restrict__ xT,
                                                      const float* __restrict__ demod,
                                                      float* __restrict__ out) {
  __shared__ unsigned short lA[3 * 128 * 32];   // 24576 B
  __shared__ unsigned short lB[258 * 32];       // 16512 B

  // XCD b-grouping: 512 blocks; ids == xcd (mod 8); 2 batches per XCD.
  const int id  = blockIdx.x;
  const int xcd = id & 7;
  const int j   = id >> 3;                 // 0..63
  const int b   = xcd + 8 * (j >> 5);      // 0..15
  const int r   = j & 31;
  const int o0  = (r >> 3) * 128;          // 4 o-blocks
  const int t0  = (r & 7) * 256;           // 8 t-blocks

  const int tid  = threadIdx.x;
  const int lane = tid & 63;
  const int wm   = ((tid >> 6) & 1) * 64;  // wave o offset
  const int wn   = (tid >> 7) * 128;       // wave t offset
  const int rl   = lane & 15;
  const int kc   = lane >> 4;              // chunk 0..3 within 32-wide row

  const unsigned short* gW = Wb + (size_t)o0 * 512;            // batch-independent
  const unsigned short* gX = xT + ((size_t)b * TP + t0) * CIN;

  f32x4 acc[8][4];                         // [t-frag][o-frag]
  #pragma unroll
  for (int i = 0; i < 8; ++i)
    #pragma unroll
    for (int jj = 0; jj < 4; ++jj) acc[i][jj] = (f32x4){0.f, 0.f, 0.f, 0.f};

  for (int kk = 0; kk < 16; ++kk) {
    const int i0 = kk * 32;
    __syncthreads();                       // previous compute done
    // A: 1536 16B-chunks, 6 per thread. chunk ci=(tap*128+ar)*4+c
    #pragma unroll
    for (int q = 0; q < 6; ++q) {
      const int ci  = q * 256 + tid;
      const int row = ci >> 2;             // tap*128 + ar
      const int tap = row >> 7;
      const int ar  = row & 127;
      const int gc  = ((ci & 3) ^ ((ar >> 1) & 3)) * 8;
      __builtin_amdgcn_global_load_lds(
          (const AS1 void*)(gW + (size_t)tap * 262144 + (size_t)ar * 512 + i0 + gc),
          (AS3 void*)(&lA[ci * 8]), 16, 0, 0);
    }
    // B: 258 rows x 4 chunks = 1032; 4 per thread + tail 8
    #pragma unroll
    for (int q = 0; q < 4; ++q) {
      const int ci  = q * 256 + tid;
      const int row = ci >> 2;
      const int gc  = ((ci & 3) ^ ((row >> 1) & 3)) * 8;
      __builtin_amdgcn_global_load_lds(
          (const AS1 void*)(gX + (size_t)row * CIN + i0 + gc),
          (AS3 void*)(&lB[ci * 8]), 16, 0, 0);
    }
    if (tid < 8) {
      const int ci  = 1024 + tid;
      const int row = ci >> 2;             // 256, 257
      const int gc  = ((ci & 3) ^ ((row >> 1) & 3)) * 8;
      __builtin_amdgcn_global_load_lds(
          (const AS1 void*)(gX + (size_t)row * CIN + i0 + gc),
          (AS3 void*)(&lB[ci * 8]), 16, 0, 0);
    }
    __syncthreads();                       // staging visible

    #pragma unroll
    for (int tap = 0; tap < 3; ++tap) {
      bf16x8 wf[4], xf[8];
      #pragma unroll
      for (int ni = 0; ni < 4; ++ni) {
        const int ra = wm + ni * 16 + rl;
        wf[ni] = *(const bf16x8*)&lA[((tap * 128 + ra) * 4 + (kc ^ ((ra >> 1) & 3))) * 8];
      }
      #pragma unroll
      for (int mi = 0; mi < 8; ++mi) {
        const int rb = wn + mi * 16 + rl + tap;
        xf[mi] = *(const bf16x8*)&lB[(rb * 4 + (kc ^ ((rb >> 1) & 3))) * 8];
      }
      #pragma unroll
      for (int mi = 0; mi < 8; ++mi)
        #pragma unroll
        for (int ni = 0; ni < 4; ++ni)
          acc[mi][ni] = __builtin_amdgcn_mfma_f32_16x16x32_bf16(xf[mi], wf[ni], acc[mi][ni], 0, 0, 0);
    }
  }

  // epilogue: D col = lane&15 -> o; row = (lane>>4)*4+reg -> t (f32x4 stores)
  const int ccol = lane & 15;
  const int trow = (lane >> 4) * 4;
  float dmv[4];
  #pragma unroll
  for (int ni = 0; ni < 4; ++ni)
    dmv[ni] = demod[(size_t)b * 512 + o0 + wm + ni * 16 + ccol];
  float* ob = out + ((size_t)b * COUT + o0 + wm + ccol) * T_ + t0 + wn + trow;
  #pragma unroll
  for (int mi = 0; mi < 8; ++mi)
    #pragma unroll
    for (int ni = 0; ni < 4; ++ni) {
      f32x4 v = acc[mi][ni];
      v.x *= dmv[ni]; v.y *= dmv[ni]; v.z *= dmv[ni]; v.w *= dmv[ni];
      *(f32x4*)&ob[(size_t)ni * 16 * T_ + mi * 16] = v;
    }
}

// ---------------------------------------------------------------------------
extern "C" void kernel_launch(void* const* d_in, const int* in_sizes, int n_in,
                              void* d_out, int out_size, void* d_ws, size_t ws_size,
                              hipStream_t stream) {
  const float* x       = (const float*)d_in[0];   // [16,512,2048]
  const float* c_src   = (const float*)d_in[1];   // [16,128]
  const float* c_trg   = (const float*)d_in[2];   // [16,128]
  const float* style_w = (const float*)d_in[3];   // [512,256]
  const float* style_b = (const float*)d_in[4];   // [512]
  const float* weight  = (const float*)d_in[5];   // [1,512,512,3]
  float* out = (float*)d_out;

  // workspace: s fp32 [16][512] @0; demod fp32 [16][512] @32768;
  //            Wb bf16 [3][512][512] @65536; xT bf16 [16][2050][512] @1638400
  char* ws = (char*)d_ws;
  float* s_buf          = (float*)ws;
  float* demod_buf      = (float*)(ws + 32768);
  unsigned short* Wb    = (unsigned short*)(ws + 65536);
  unsigned short* xTbuf = (unsigned short*)(ws + 65536 + 1572864);

  style_kernel<<<dim3(8, 16), 256, 0, stream>>>(c_src, c_trg, style_w, style_b, s_buf);
  fused_prep_kernel<<<dim3(4608), 256, 0, stream>>>(x, s_buf, weight, xTbuf,
                                                    demod_buf, Wb);
  gemm_kernel<<<dim3(512), 256, 0, stream>>>(Wb, xTbuf, demod_buf, out);
}